// Round 8
// baseline (1377.499 us; speedup 1.0000x reference)
//
#include <hip/hip_runtime.h>

// R22: 4-wave block = {2-gate set} x {sequence}; pipelined tails; minimal
// per-wave register pressure.
//
// R21 post-mortem: VGPR_Count=96 with ~135 pressure -> the RA parks weights
// in AGPRs even UNDER the 128 cap; "+v" pins only force VGPR at use sites,
// so every use pays v_accvgpr_read shuttles (R16's ledger closed at ~300
// shuttle-cyc/wave-step the same way). Zero parking requires pressure
// comfortably under the grant (~90), not just <=128.
//
// Design: w0={I,F}/seqA (+tail A, z(A) in-register), w1={G,O}/seqA (push),
// w2={I,F}/seqB (+tail B), w3={G,O}/seqB (push). 52 weight floats/wave
// (26 v2f) + ~35 working ~= 87 pressure -> no parking. Grid 1024 blocks x
// 4 waves = 4096 waves = 4/SIMD (vs R21's 2): dynamic latency hiding for
// the barrier skew and trans chains. Protocol is R21's verbatim:
//   TAIL(t-1) [w0,w2]  B1  matvec(t) [all] + push [w1,w3]  B2  pull [w0,w2]
// xch needs no parity (B1 separates pull(t) from push(t+1)); hrow is
// parity-double-buffered by the same `par ^= 1`. z never touches LDS
// (tail waves own their I-gate partials incl. z-rows -> 4 readlanes).
//
// Ledger carried: VALU cannot source AGPRs on gfx950 (R13/R19); grant at
// waves_per_eu(2) = 128 >= 87 pressure; per-gate pk x/y accumulation order
// preserved -> bit-identical (absmax 0.0002441406).

#define H1N  51
#define NP   26    // k-pairs: k=0..51; k=51 slot = bias (hrow[51]=1.0)
#define NQ   13    // k-quads for the b128 hrow broadcast reads
#define WAVE 64

typedef float v2f __attribute__((ext_vector_type(2)));
typedef float v4f __attribute__((ext_vector_type(4)));

#define INV_LN2   1.44269504088896340736f
#define INV_LN2X2 2.88539008177792681472f

__device__ __forceinline__ float sigmoid_s(float xs) {   // input pre-scaled by 1/ln2
    return __builtin_amdgcn_rcpf(1.0f + __builtin_amdgcn_exp2f(-xs));
}
__device__ __forceinline__ float tanh_s2(float xs2) {    // input pre-scaled by 2/ln2
    float e = __builtin_amdgcn_exp2f(xs2);
    return fmaf(-2.0f, __builtin_amdgcn_rcpf(e + 1.0f), 1.0f);
}
__device__ __forceinline__ float tanh_nat(float x) {
    return tanh_s2(x * INV_LN2X2);
}
__device__ __forceinline__ float rdlane(float v, int k) {
    return __int_as_float(__builtin_amdgcn_readlane(__float_as_int(v), k));
}

__global__ __attribute__((amdgpu_flat_work_group_size(256, 256),
                          amdgpu_waves_per_eu(2)))
void lstm_q4(const float* __restrict__ input,   // [B, T]
             const float* __restrict__ W_ih1,   // [204, 1]
             const float* __restrict__ W_hh1,   // [204, 51]
             const float* __restrict__ b_ih1,   // [204]
             const float* __restrict__ b_hh1,   // [204]
             const float* __restrict__ W_ih2,   // [4, 51]
             const float* __restrict__ W_hh2,   // [4, 1]
             const float* __restrict__ b_ih2,   // [4]
             const float* __restrict__ b_hh2,   // [4]
             float* __restrict__ out,           // [B, T+F]
             int T, int TF)
{
    const int tid = threadIdx.x;
    const int j   = tid & (WAVE - 1);
    const int wid = tid >> 6;
    const int myseq = wid >> 1;                 // waves 0,1 -> A; 2,3 -> B
    const bool isIF = ((wid & 1) == 0);         // I,F holder = tail wave
    const bool jv = (j < H1N);
    const int jj  = jv ? j : 0;
    const float m = jv ? 1.0f : 0.0f;
    const bool isz = (j >= H1N) && (j < H1N + 4);   // z-row lanes 51..54
    const int  q   = isz ? (j - H1N) : 0;
    const float mz  = isz ? 1.0f : 0.0f;
    const float mzA = isIF ? mz : 0.0f;             // z fold in the I-gate slot
    const float s2q = (q == 2) ? INV_LN2X2 : INV_LN2;  // LSTM2 gate scale

    // This wave's two gate rows: A = I or G, B = F or O.
    const int rA = (isIF ? 0 : 2*H1N)   + jj;
    const int rB = (isIF ? H1N : 3*H1N) + jj;
    const float sclA = isIF ? INV_LN2 : INV_LN2X2;  // G is the tanh gate
    const float sclB = INV_LN2;

    __shared__ __align__(16) float hrow[2][2][WAVE];   // [seq][par][lane]
    __shared__ __align__(16) float xch[2][WAVE][2];    // [seq][lane][G,O]

    // 52 weight floats in VGPRs -- pressure ~87 total, below the parking
    // threshold. Bias folded into the k=51 slot (hrow[51]==1.0); IF-waves'
    // z-lanes carry W_ih2 row q in the I slot.
    v2f wA[NP], wB[NP];
#pragma unroll
    for (int kk = 0; kk < NP; ++kk) {
        const int k0 = 2*kk, k1 = k0 + 1;
        wA[kk].x = m*sclA*W_hh1[rA*H1N + k0] + mzA*s2q*W_ih2[q*H1N + k0];
        wB[kk].x = m*sclB*W_hh1[rB*H1N + k0];
        if (k1 < H1N) {
            wA[kk].y = m*sclA*W_hh1[rA*H1N + k1] + mzA*s2q*W_ih2[q*H1N + k1];
            wB[kk].y = m*sclB*W_hh1[rB*H1N + k1];
        } else {   // k1 == 51: bias slot; z-rows get 0
            wA[kk].y = m*sclA*(b_ih1[rA] + b_hh1[rA]);
            wB[kk].y = m*sclB*(b_ih1[rB] + b_hh1[rB]);
        }
    }
#pragma unroll
    for (int kk = 0; kk < NP; ++kk)
        asm volatile("" : "+v"(wA[kk]), "+v"(wB[kk]));   // pin: no remat

    // x-side weights (tail waves use them; init-only cost for helpers).
    const float wx_i = m*INV_LN2  *W_ih1[jj];
    const float wx_f = m*INV_LN2  *W_ih1[H1N + jj];
    const float wx_g = m*INV_LN2X2*W_ih1[2*H1N + jj];
    const float wx_o = m*INV_LN2  *W_ih1[3*H1N + jj];

    // LSTM2 thread-uniform scalars (SGPRs), pre-scaled.
    const float wh2_0 = INV_LN2*W_hh2[0], wh2_1 = INV_LN2*W_hh2[1];
    const float wh2_2 = INV_LN2X2*W_hh2[2], wh2_3 = INV_LN2*W_hh2[3];
    const float b2_0 = INV_LN2*(b_ih2[0] + b_hh2[0]), b2_1 = INV_LN2*(b_ih2[1] + b_hh2[1]);
    const float b2_2 = INV_LN2X2*(b_ih2[2] + b_hh2[2]), b2_3 = INV_LN2*(b_ih2[3] + b_hh2[3]);

    // Init both parities of my seq's hrow (tail waves own the write side).
    if (isIF) {
        const float e = (j == H1N) ? 1.0f : 0.0f;   // bias lane, never rewritten
        hrow[myseq][0][j] = e;
        hrow[myseq][1][j] = e;
    }
    __syncthreads();

    const int s = 2 * blockIdx.x + myseq;
    const float* __restrict__ xrow = input + (long)s * T;
    float* __restrict__ orow = out + (long)s * TF;

    float c1 = 0.0f, h2 = 0.0f, c2 = 0.0f, obuf = 0.0f, xbuf = 0.0f;
    float ownA = 0.0f, ownB = 0.0f, rdA = 0.0f, rdB = 0.0f;
    float zA0 = 0.0f, zA1 = 0.0f, zA2 = 0.0f, zA3 = 0.0f;

    int par = 1;   // slot matvec(0) reads (h1(-1) lives at parity (-1)&1 = 1)

    // matvec(t) on my seq's hrow (my two gates) + push/pull across B2.
    auto MVX = [&]() {
        v2f aA = {0.0f, 0.0f}, aB = {0.0f, 0.0f};
        const float* __restrict__ hb = &hrow[myseq][par][0];
#pragma unroll
        for (int kq = 0; kq < NQ; ++kq) {
            const v4f h4 = *(const v4f*)&hb[4*kq];        // ds_read_b128 bcast
            const v2f hp0 = __builtin_shufflevector(h4, h4, 0, 1);
            const v2f hp1 = __builtin_shufflevector(h4, h4, 2, 3);
            asm("v_pk_fma_f32 %0, %2, %4, %0\n\t"
                "v_pk_fma_f32 %1, %3, %4, %1"
                : "+v"(aA), "+v"(aB)
                : "v"(wA[2*kq]), "v"(wB[2*kq]), "v"(hp0));
            asm("v_pk_fma_f32 %0, %2, %4, %0\n\t"
                "v_pk_fma_f32 %1, %3, %4, %1"
                : "+v"(aA), "+v"(aB)
                : "v"(wA[2*kq+1]), "v"(wB[2*kq+1]), "v"(hp1));
        }
        const float sA_ = aA.x + aA.y;
        const float sB_ = aB.x + aB.y;
        if (isIF) {                               // keep I,F; z in-register
            ownA = sA_; ownB = sB_;
            zA0 = rdlane(sA_, H1N + 0);
            zA1 = rdlane(sA_, H1N + 1);
            zA2 = rdlane(sA_, H1N + 2);
            zA3 = rdlane(sA_, H1N + 3);
        } else {                                  // push G,O to tail wave
            v2f pr; pr.x = sA_; pr.y = sB_;
            *(v2f*)&xch[myseq][j][0] = pr;        // ds_write_b64
        }
        __syncthreads();                          // B2: partials visible
        if (isIF) {
            const v2f mo = *(const v2f*)&xch[myseq][j][0];
            rdA = mo.x; rdB = mo.y;
        }
    };

    // Tail (tail waves only): [LSTM2(t-1) if do_l2] + [LSTM1 fin(t) if
    // do_fin]. Writes h1(t) to hrow[myseq][par] = the slot matvec(t+1)
    // reads after B1.
    auto TAIL = [&](int t, int do_l2, int do_fin, int xmode) {
        const float mI = ownA, mF = ownB, mG = rdA, mO = rdB;

        if (do_l2) {                              // LSTM2 step t-1
            const float g2i = sigmoid_s(fmaf(wh2_0, h2, b2_0 + zA0));
            const float g2f = sigmoid_s(fmaf(wh2_1, h2, b2_1 + zA1));
            const float g2g = tanh_s2 (fmaf(wh2_2, h2, b2_2 + zA2));
            const float g2o = sigmoid_s(fmaf(wh2_3, h2, b2_3 + zA3));
            c2 = fmaf(g2f, c2, g2i * g2g);
            h2 = g2o * tanh_nat(c2);
            obuf = (j == ((t - 1) & 63)) ? h2 : obuf;   // pack out(t-1)
            if ((t & 63) == 0) orow[t - 64 + j] = obuf; // flush t-64..t-1
        }
        if (do_fin) {                             // LSTM1 step t
            float x;
            if (xmode == 0) {
                if ((t & 63) == 0) xbuf = xrow[t + j];
                x = rdlane(xbuf, t & 63);
            } else {
                x = h2;                           // feedback
            }
            const float gi = sigmoid_s(fmaf(wx_i, x, mI));
            const float gf = sigmoid_s(fmaf(wx_f, x, mF));
            const float gg = tanh_s2 (fmaf(wx_g, x, mG));
            const float go = sigmoid_s(fmaf(wx_o, x, mO));
            c1 = fmaf(gf, c1, gi * gg);
            const float h1 = go * tanh_nat(c1);
            if (jv) hrow[myseq][par][j] = h1;     // publish h1(t)
        }
    };

    // ---- iter 0: matvec(0) only (reads h1(-1) at par=1) ----
    MVX(); par ^= 1;

    // ---- iter 1: tail(0) [no LSTM2], matvec(1) ----
    if (isIF) TAIL(0, 0, 1, 0);
    __syncthreads();                              // B1
    MVX(); par ^= 1;

    // ---- warm: iters n=2..T (t = 1..T-1, x from input) ----
    for (int n = 2; n <= T; ++n) {
        if (isIF) TAIL(n - 1, 1, 1, 0);
        __syncthreads();                          // B1: h1 visible to partner
        MVX(); par ^= 1;
    }

    // ---- future: iters n=T+1..TF (t = T..TF-1, x = h2 feedback) ----
    for (int n = T + 1; n <= TF; ++n) {
        if (isIF) TAIL(n - 1, 1, 1, 1);
        __syncthreads();                          // B1
        MVX(); par ^= 1;
    }

    // ---- final: LSTM2(TF-1) + last flush (no LSTM1 fin) ----
    if (isIF) TAIL(TF, 1, 0, 1);
}

extern "C" void kernel_launch(void* const* d_in, const int* in_sizes, int n_in,
                              void* d_out, int out_size, void* d_ws, size_t ws_size,
                              hipStream_t stream) {
    const float* input = (const float*)d_in[0];
    const float* W_ih1 = (const float*)d_in[1];
    const float* W_hh1 = (const float*)d_in[2];
    const float* b_ih1 = (const float*)d_in[3];
    const float* b_hh1 = (const float*)d_in[4];
    const float* W_ih2 = (const float*)d_in[5];
    const float* W_hh2 = (const float*)d_in[6];
    const float* b_ih2 = (const float*)d_in[7];
    const float* b_hh2 = (const float*)d_in[8];
    float* out = (float*)d_out;

    const int B  = 2048;
    const int T  = in_sizes[0] / B;      // 1024
    const int TF = out_size   / B;       // 1088

    lstm_q4<<<dim3(B / 2), dim3(4 * WAVE), 0, stream>>>(
        input, W_ih1, W_hh1, b_ih1, b_hh1, W_ih2, W_hh2, b_ih2, b_hh2,
        out, T, TF);
}